// Round 7
// baseline (403.121 us; speedup 1.0000x reference)
//
#include <hip/hip_runtime.h>
#include <hip/hip_bf16.h>

typedef __attribute__((ext_vector_type(8))) short short8;
typedef __attribute__((ext_vector_type(4))) float f32x4;

__device__ inline unsigned short f2bf(float x) {
  unsigned u = __float_as_uint(x);
  unsigned rounding = 0x7FFFu + ((u >> 16) & 1u);
  return (unsigned short)((u + rounding) >> 16);
}
__device__ inline float bf2f(unsigned short u) {
  return __uint_as_float(((unsigned)u) << 16);
}
__device__ inline void gload_lds16(const void* g, void* l) {
  __builtin_amdgcn_global_load_lds(
      (const __attribute__((address_space(1))) unsigned int*)g,
      (__attribute__((address_space(3))) unsigned int*)l, 16, 0, 0);
}

#define KPAD 5440   // 5408 padded to 85*64
#define NPAD 4864   // 4800 padded to 38*128
#define X1Q  32768  // bytes per (pair, quarter) region in X1 (28800 used)
#define SBUF 17408  // conv2 per-quarter staging buffer (17 KiB)

// ---------------------------------------------------------------------------
// Kernel 1: pair decode + rasterize + slicing output
// ---------------------------------------------------------------------------
__global__ void prep_pairs(const float* __restrict__ bboxes,
                           const int* __restrict__ num_obj, int M,
                           int* __restrict__ pairTab,
                           float* __restrict__ slicing) {
  __shared__ int cum[9];
  if (threadIdx.x == 0) {
    int c = 0; cum[0] = 0;
    for (int b = 0; b < 8; b++) { int n = num_obj[b]; c += n*(n-1)/2; cum[b+1] = c; }
  }
  __syncthreads();
  for (int m = threadIdx.x; m < M; m += blockDim.x) {
    int b = 0;
    while (b < 7 && m >= cum[b+1]) b++;
    int p = m - cum[b];
    int n = num_obj[b];
    int i = 0, rem = p;
    while (rem >= (n - 1 - i)) { rem -= (n - 1 - i); i++; }
    int j = i + 1 + rem;
    const float* A = bboxes + (b*24 + i)*4;
    const float* Bb = bboxes + (b*24 + j)*4;
    float ax1=A[0], ay1=A[1], ax2=A[2], ay2=A[3];
    float bx1=Bb[0], by1=Bb[1], bx2=Bb[2], by2=Bb[3];
    float u1 = fminf(ax1,bx1), v1 = fminf(ay1,by1);
    float u2 = fmaxf(ax2,bx2), v2 = fmaxf(ay2,by2);
    float w = u2-u1, h = v2-v1;
    float scale = 63.0f / fmaxf(fmaxf(w,h), 1e-6f);
    float offx = (h >= w) ? __fmul_rn(63.0f - __fmul_rn(w,scale), 0.5f) : 0.0f;
    float offy = (w > h)  ? __fmul_rn(63.0f - __fmul_rn(h,scale), 0.5f) : 0.0f;
    int* t = pairTab + m*8;
    t[0] = (int)rintf(__fadd_rn(__fmul_rn(ax1-u1, scale), offx));
    t[1] = (int)rintf(__fadd_rn(__fmul_rn(ay1-v1, scale), offy));
    t[2] = (int)rintf(__fadd_rn(__fmul_rn(ax2-u1, scale), offx));
    t[3] = (int)rintf(__fadd_rn(__fmul_rn(ay2-v1, scale), offy));
    t[4] = (int)rintf(__fadd_rn(__fmul_rn(bx1-u1, scale), offx));
    t[5] = (int)rintf(__fadd_rn(__fmul_rn(by1-v1, scale), offy));
    t[6] = (int)rintf(__fadd_rn(__fmul_rn(bx2-u1, scale), offx));
    t[7] = (int)rintf(__fadd_rn(__fmul_rn(by2-v1, scale), offy));
    slicing[m*3+0] = (float)b;
    slicing[m*3+1] = (float)i;
    slicing[m*3+2] = (float)j;
  }
}

// ---------------------------------------------------------------------------
// Kernel 2: conv1 range-sum table T[c][ry26][rx26][64] (+half conv1 bias in
// each of c=0/1) + conv2 weights reorder W2B (zero when kyx>=25, K padding)
// ---------------------------------------------------------------------------
__global__ void prep_tables(const float* __restrict__ w1, const float* __restrict__ b1,
                            const float* __restrict__ w2,
                            float* __restrict__ T, unsigned short* __restrict__ W2B) {
  int idx = blockIdx.x*256 + threadIdx.x;
  if (idx < 86528) {
    int o = idx & 63;
    int t = idx >> 6;
    int rxi = t % 26; t /= 26;
    int ryi = t % 26;
    int c = t / 26;
    int ky0 = ryi/5, ky1 = ryi%5, kx0 = rxi/5, kx1 = rxi%5;
    float s = 0.f;
    for (int ky = ky0; ky <= ky1; ky++)
      for (int kx = kx0; kx <= kx1; kx++)
        s += w1[((o*2 + c)*5 + ky)*5 + kx];
    T[idx] = s + 0.5f * b1[o];
  } else if (idx < 86528 + 53248) {
    int i = idx - 86528;
    int j = i & 7;
    int ln = (i >> 3) & 63;
    int r1 = i >> 9;
    int mt = r1 & 1;
    int r2 = r1 >> 1;
    int s = r2 % 13;
    int pp = r2 / 13;
    int oc = mt*16 + (ln & 15);
    int q = ln >> 4;
    int kyx = 2*s + (q >> 1);
    int ic = pp*16 + ((q & 1) << 3) + j;
    float val = 0.f;
    if (kyx < 25) val = w2[((oc*64 + ic)*5 + kyx/5)*5 + (kyx%5)];
    W2B[i] = f2bf(val);
  }
}

// ---------------------------------------------------------------------------
// Kernel 3: transpose+cast lin_w [5408][4800] f32 -> Wt [4800][KPAD] bf16
// ---------------------------------------------------------------------------
__global__ __launch_bounds__(256) void prep_wt(const float* __restrict__ lw,
                                               unsigned short* __restrict__ Wt) {
  __shared__ unsigned short tile[64][65];
  int k0 = blockIdx.x*64, n0 = blockIdx.y*64;
  for (int i = threadIdx.x; i < 64*64; i += 256) {
    int r = i >> 6, cdx = i & 63;
    int k = k0 + r, n = n0 + cdx;
    float v = (k < 5408) ? lw[(size_t)k*4800 + n] : 0.f;
    tile[r][cdx] = f2bf(v);
  }
  __syncthreads();
  for (int i = threadIdx.x; i < 64*64; i += 256) {
    int r = i >> 6, cdx = i & 63;
    int n = n0 + r, k = k0 + cdx;
    Wt[(size_t)n*KPAD + k] = tile[cdx][r];
  }
}

// ---------------------------------------------------------------------------
// Kernel 4a: conv1 (table lookup, bias folded) + relu + pool1.
// One block per (pair, quarter); 2160 blocks, 256 threads, no accumulator ->
// ~50 regs, full occupancy. Output X1 in LDS-linear SWIZZLED byte order so
// conv2 can stage it with plain linear global_load_lds.
// ---------------------------------------------------------------------------
__global__ __launch_bounds__(256) void conv1_pool(
    const int* __restrict__ pairTab, const float* __restrict__ T,
    unsigned short* __restrict__ X1) {
  __shared__ unsigned char rIdx[4][64];
  int blk = blockIdx.x;
  int m = blk >> 2, pp = blk & 3;
  int tid = threadIdx.x;
  const int* pt = pairTab + m*8;

  if (tid < 240) {
    int qq = tid % 60, which = tid / 60;
    int lo, hi;
    if (which == 0)      { lo = pt[1]; hi = pt[3]; }
    else if (which == 1) { lo = pt[5]; hi = pt[7]; }
    else if (which == 2) { lo = pt[0]; hi = pt[2]; }
    else                 { lo = pt[4]; hi = pt[6]; }
    int k0 = lo - qq; if (k0 < 0) k0 = 0;
    int k1 = hi - qq; if (k1 > 4) k1 = 4;
    rIdx[which][qq] = (k0 > k1) ? (unsigned char)25 : (unsigned char)(k0*5 + k1);
  }
  __syncthreads();

  char* X1q = (char*)X1 + (size_t)blk * X1Q;
  for (int item = tid; item < 1800; item += 256) {
    int pos = item >> 1;
    int icg = item & 1;
    int ch0 = pp*16 + icg*8;
    int py = pos / 30, px = pos % 30;
    float best[8];
#pragma unroll
    for (int j = 0; j < 8; j++) best[j] = -1e30f;
#pragma unroll
    for (int d = 0; d < 4; d++) {
      int y = py*2 + (d>>1), x = px*2 + (d&1);
      int rya = rIdx[0][y], ryb = rIdx[1][y];
      int rxa = rIdx[2][x], rxb = rIdx[3][x];
      const float* Ta = T + (((rya)*26 + rxa)<<6) + ch0;
      const float* Tb = T + (((26 + ryb)*26 + rxb)<<6) + ch0;
      f32x4 a0 = *(const f32x4*)Ta, a1 = *(const f32x4*)(Ta+4);
      f32x4 c0 = *(const f32x4*)Tb, c1 = *(const f32x4*)(Tb+4);
#pragma unroll
      for (int j = 0; j < 4; j++) {
        best[j]   = fmaxf(best[j],   a0[j]+c0[j]);
        best[4+j] = fmaxf(best[4+j], a1[j]+c1[j]);
      }
    }
    short8 v;
#pragma unroll
    for (int j = 0; j < 8; j++)
      v[j] = (short)f2bf(fmaxf(best[j], 0.f));
    int byte = pos*32 + ((icg ^ ((pos>>2)&1))<<4);
    *(short8*)(X1q + byte) = v;
  }
}

// ---------------------------------------------------------------------------
// Kernel 4b: conv2 via MFMA + pool2. One block per (pair, oy-half):
// grid 2M, 256 threads (4 waves). Half h=0 covers oy 0..13 (pool rows 0..6),
// h=1 covers oy 14..25 (pool rows 7..12) -> pool pairs never straddle.
// Each half stages only input rows [row0, row0+~17*30) per quarter: 17KB
// buffers, dbuf 34.8KB -> 4 blocks/CU, 16 waves/CU (vs 2 blocks before).
// NO min-wave launch_bounds (rounds 3-5 spill lesson).
// ---------------------------------------------------------------------------
__global__ __launch_bounds__(256) void conv2_mfma(
    const unsigned short* __restrict__ X1, const unsigned short* __restrict__ W2B,
    const float* __restrict__ b2, unsigned short* __restrict__ X, int M) {
  __shared__ char smem[2*SBUF];   // 34.8KB: staging dbuf; stage3 reuses (23.3KB)
  int blk = blockIdx.x;
  int m = blk >> 1, h = blk & 1;
  int tid = threadIdx.x, lane = tid & 63, wid = tid >> 6;
  const char* X1m = (const char*)X1 + (size_t)m*4*X1Q;

  int oy0    = h ? 14 : 0;
  int npos   = h ? 312 : 364;     // 12x26 / 14x26 output positions
  int ntiles = h ? 20 : 23;
  int row0   = h ? 416 : 0;       // (oy0*30) & ~15 (16-aligned for swizzle)
  int ncall  = h ? 16 : 17;       // 1KB gload_lds calls per quarter

  int tbase = ntiles >> 2, trem = ntiles & 3;
  int ntile  = tbase + (wid < trem ? 1 : 0);
  int tstart = (wid < trem) ? wid*(tbase+1) : trem*(tbase+1) + (wid-trem)*tbase;

  int rowbase[6];
#pragma unroll
  for (int tt = 0; tt < 6; tt++) {
    int pos = (tstart + tt)*16 + (lane & 15);
    if (pos > npos-1) pos = npos-1;
    int oy = oy0 + pos/26;
    rowbase[tt] = oy*30 + pos%26;
  }
  f32x4 acc[6][2];
#pragma unroll
  for (int tt = 0; tt < 6; tt++) {
    acc[tt][0] = (f32x4){0.f,0.f,0.f,0.f};
    acc[tt][1] = (f32x4){0.f,0.f,0.f,0.f};
  }

  int q = lane >> 4, qh = q >> 1, qs = q & 1;

  auto stageq = [&](int buf, int qtr) {
    const char* src = X1m + (size_t)qtr * X1Q + row0*32;
    char* dst = smem + buf * SBUF;
#pragma unroll
    for (int c = 0; c < 5; c++) {
      int chunk = wid + c*4;
      if (chunk < ncall)
        gload_lds16(src + chunk*1024 + lane*16, dst + chunk*1024);
    }
  };

  stageq(0, 0);
  __syncthreads();                          // drains vmcnt (gload_lds) too
  for (int pp = 0; pp < 4; pp++) {
    if (pp < 3) stageq((pp+1) & 1, pp+1);   // prefetch next quarter
    const char* pb = smem + (pp & 1) * SBUF;
    for (int s = 0; s < 13; s++) {
      const unsigned short* wptr = W2B + (size_t)(pp*13 + s)*1024 + lane*8;
      short8 a0 = *(const short8*)wptr;
      short8 a1 = *(const short8*)(wptr + 512);
      int kyx = 2*s + qh; if (kyx > 24) kyx = 24;
      int radd = (kyx/5)*30 + (kyx%5);
#pragma unroll
      for (int tt = 0; tt < 6; tt++) {
        if (tt < ntile) {
          int row = rowbase[tt] + radd;
          int byte = (row - row0)*32 + ((qs ^ ((row>>2)&1))<<4);
          short8 bv = *(const short8*)(pb + byte);
          acc[tt][0] = __builtin_amdgcn_mfma_f32_16x16x32_bf16(a0, bv, acc[tt][0], 0, 0, 0);
          acc[tt][1] = __builtin_amdgcn_mfma_f32_16x16x32_bf16(a1, bv, acc[tt][1], 0, 0, 0);
        }
      }
    }
    __syncthreads();
  }
  // stage3: dump conv2 (pre-bias) to LDS bf16 [32][npos]
  unsigned short* p1 = (unsigned short*)smem;
#pragma unroll
  for (int tt = 0; tt < 6; tt++) {
    if (tt < ntile) {
      int pos = (tstart + tt)*16 + (lane & 15);
      if (pos < npos) {
#pragma unroll
        for (int mt = 0; mt < 2; mt++)
#pragma unroll
          for (int r = 0; r < 4; r++) {
            int oc = mt*16 + q*4 + r;
            p1[oc*npos + pos] = f2bf(acc[tt][mt][r]);
          }
      }
    }
  }
  __syncthreads();
  // pool2 + bias + relu -> X[m][KPAD] bf16 (this half's pool rows only)
  int nout = h ? 6 : 7;     // pool output rows in this half
  int oypb = h ? 7 : 0;
  for (int f = tid; f < 32*nout*13; f += 256) {
    int ocl = f / (nout*13), rem2 = f % (nout*13);
    int oyl = rem2 / 13, px = rem2 % 13;
    int oyp = oypb + oyl;
    int posl = (oyp*2 - oy0)*26 + px*2;
    const unsigned short* c2 = p1 + ocl*npos + posl;
    float v = fmaxf(fmaxf(bf2f(c2[0]), bf2f(c2[1])), fmaxf(bf2f(c2[26]), bf2f(c2[27])));
    X[(size_t)m*KPAD + ocl*169 + oyp*13 + px] = f2bf(fmaxf(v + b2[ocl], 0.f));
  }
  if (h == 0 && tid < 32) X[(size_t)m*KPAD + 5408 + tid] = 0;
}

// ---------------------------------------------------------------------------
// Kernel 5: linear GEMM, split-K, 2-phase pipelined.
// BM=64, BN=128, BK=64, 4 waves (2x2), each wave 32x64.
// ---------------------------------------------------------------------------
__global__ __launch_bounds__(256) void gemm_lin(
    const unsigned short* __restrict__ X, const unsigned short* __restrict__ Wt,
    const float* __restrict__ lin_b, float* __restrict__ P, float* __restrict__ out,
    int M, int Mpad, int splits) {
  __shared__ unsigned short As[2][4096];   //  8KB x2: 64 rows x 64 k
  __shared__ unsigned short Bs[2][8192];   // 16KB x2: 128 rows x 64 k
  int tid = threadIdx.x, lane = tid & 63, wid = tid >> 6;
  int m0 = blockIdx.x * 64, n0 = blockIdx.y * 128;
  int ks = blockIdx.z;
  int itBeg = (ks * 85) / splits, itEnd = ((ks + 1) * 85) / splits;
  int wm = wid >> 1, wn = wid & 1;

  f32x4 acc[2][4];
#pragma unroll
  for (int i = 0; i < 2; i++)
#pragma unroll
    for (int j = 0; j < 4; j++) acc[i][j] = (f32x4){0.f,0.f,0.f,0.f};

  int rsub = lane >> 3;
  int kslot = (lane & 7) ^ rsub;
  int kg = lane >> 4;

  auto stage = [&](int buf, int it) {
    size_t kof = (size_t)it * 64 + kslot * 8;
#pragma unroll
    for (int cc = 0; cc < 2; cc++) {
      int chunk = wid + cc*4;
      int gm = m0 + chunk*8 + rsub;
      gload_lds16(X + (size_t)gm*KPAD + kof, (char*)As[buf] + chunk*1024);
    }
#pragma unroll
    for (int cc = 0; cc < 4; cc++) {
      int chunk = wid + cc*4;
      int gn = n0 + chunk*8 + rsub;
      gload_lds16(Wt + (size_t)gn*KPAD + kof, (char*)Bs[buf] + chunk*1024);
    }
  };

  stage(0, itBeg);
  __syncthreads();
  int cur = 0;
  for (int it = itBeg; it < itEnd; ++it) {
    if (it + 1 < itEnd) stage(cur ^ 1, it + 1);
#pragma unroll
    for (int ksub = 0; ksub < 2; ++ksub) {
      int slot = ksub*4 + kg;
      short8 af[2], bfr[4];
#pragma unroll
      for (int mf = 0; mf < 2; mf++) {
        int r = wm*32 + mf*16 + (lane & 15);
        af[mf] = *(const short8*)((const char*)As[cur] + r*128 + ((slot ^ (lane&7))<<4));
      }
#pragma unroll
      for (int nf = 0; nf < 4; nf++) {
        int r = wn*64 + nf*16 + (lane & 15);
        bfr[nf] = *(const short8*)((const char*)Bs[cur] + r*128 + ((slot ^ (lane&7))<<4));
      }
#pragma unroll
      for (int mf = 0; mf < 2; mf++)
#pragma unroll
        for (int nf = 0; nf < 4; nf++)
          acc[mf][nf] = __builtin_amdgcn_mfma_f32_16x16x32_bf16(af[mf], bfr[nf], acc[mf][nf], 0, 0, 0);
    }
    __syncthreads();
    cur ^= 1;
  }

  if (splits == 1) {
#pragma unroll
    for (int mf = 0; mf < 2; mf++)
#pragma unroll
      for (int nf = 0; nf < 4; nf++) {
        int n = n0 + wn*64 + nf*16 + (lane & 15);
#pragma unroll
        for (int r = 0; r < 4; r++) {
          int mm = m0 + wm*32 + mf*16 + ((lane>>4)<<2) + r;
          if (mm < M && n < 4800)
            out[(size_t)mm*4800 + n] = fmaxf(acc[mf][nf][r] + lin_b[n], 0.f);
        }
      }
  } else {
    float* Pp = P + (size_t)ks * Mpad * NPAD;
#pragma unroll
    for (int mf = 0; mf < 2; mf++)
#pragma unroll
      for (int nf = 0; nf < 4; nf++) {
        int n = n0 + wn*64 + nf*16 + (lane & 15);
#pragma unroll
        for (int r = 0; r < 4; r++) {
          int mm = m0 + wm*32 + mf*16 + ((lane>>4)<<2) + r;
          Pp[(size_t)mm*NPAD + n] = acc[mf][nf][r];
        }
      }
  }
}

// ---------------------------------------------------------------------------
// Kernel 6: split-K reduce + bias + relu
// ---------------------------------------------------------------------------
__global__ void reduce_out(const float* __restrict__ P, const float* __restrict__ lb,
                           float* __restrict__ out, int M, int Mpad, int splits) {
  int total = M * 1200;  // float4 granules
  for (int idx = blockIdx.x*256 + threadIdx.x; idx < total; idx += gridDim.x*256) {
    int m = idx / 1200, qq = idx - m*1200;
    int n = qq * 4;
    f32x4 s = *(const f32x4*)(P + (size_t)m*NPAD + n);
    for (int sidx = 1; sidx < splits; sidx++)
      s += *(const f32x4*)(P + (size_t)sidx*Mpad*NPAD + (size_t)m*NPAD + n);
    f32x4 b = *(const f32x4*)(lb + n);
    f32x4 r;
#pragma unroll
    for (int j = 0; j < 4; j++) r[j] = fmaxf(s[j] + b[j], 0.f);
    *(f32x4*)(out + (size_t)m*4800 + n) = r;
  }
}

// ---------------------------------------------------------------------------
extern "C" void kernel_launch(void* const* d_in, const int* in_sizes, int n_in,
                              void* d_out, int out_size, void* d_ws, size_t ws_size,
                              hipStream_t stream) {
  const float* bboxes = (const float*)d_in[0];
  const int*   num_obj = (const int*)d_in[1];
  const float* w1 = (const float*)d_in[2];
  const float* b1 = (const float*)d_in[3];
  const float* w2 = (const float*)d_in[4];
  const float* b2 = (const float*)d_in[5];
  const float* lw = (const float*)d_in[6];
  const float* lb = (const float*)d_in[7];
  float* out = (float*)d_out;
  int M = out_size / 4803;
  int Mpad = (M + 63) & ~63;

  auto align512 = [](size_t x) { return (x + 511) & ~(size_t)511; };
  size_t fixed = 0;
  fixed += align512((size_t)M*8*4);            // pairTab
  fixed += align512((size_t)86528*4);          // T
  fixed += align512((size_t)53248*2);          // W2B
  fixed += align512((size_t)4800*KPAD*2);      // Wt
  fixed += align512((size_t)Mpad*KPAD*2);      // X
  fixed += align512((size_t)M*4*X1Q);          // X1
  int splits = 4;
  while (splits > 1 && fixed + align512((size_t)splits*Mpad*NPAD*4) > ws_size) splits >>= 1;

  char* ws = (char*)d_ws;
  size_t off = 0;
  auto alloc = [&](size_t bytes) {
    off = align512(off);
    char* p = ws + off;
    off += bytes;
    return p;
  };
  int* pairTab = (int*)alloc((size_t)M*8*4);
  float* T = (float*)alloc((size_t)86528*4);
  unsigned short* W2B = (unsigned short*)alloc((size_t)53248*2);
  unsigned short* Wt = (unsigned short*)alloc((size_t)4800*KPAD*2);
  unsigned short* X = (unsigned short*)alloc((size_t)Mpad*KPAD*2);
  unsigned short* X1 = (unsigned short*)alloc((size_t)M*4*X1Q);
  float* P = (splits > 1) ? (float*)alloc((size_t)splits*Mpad*NPAD*4) : nullptr;

  prep_pairs<<<1, 256, 0, stream>>>(bboxes, num_obj, M, pairTab, out + (size_t)M*4800);
  prep_tables<<<(86528+53248+255)/256, 256, 0, stream>>>(w1, b1, w2, T, W2B);
  prep_wt<<<dim3(85, 75), 256, 0, stream>>>(lw, Wt);
  conv1_pool<<<M*4, 256, 0, stream>>>(pairTab, T, X1);
  conv2_mfma<<<M*2, 256, 0, stream>>>(X1, W2B, b2, X, M);
  gemm_lin<<<dim3(Mpad/64, 38, splits), 256, 0, stream>>>(X, Wt, lb, P, out, M, Mpad, splits);
  if (splits > 1)
    reduce_out<<<1024, 256, 0, stream>>>(P, lb, out, M, Mpad, splits);
}

// Round 8
// 353.129 us; speedup vs baseline: 1.1416x; 1.1416x over previous
//
#include <hip/hip_runtime.h>
#include <hip/hip_bf16.h>

typedef __attribute__((ext_vector_type(8))) short short8;
typedef __attribute__((ext_vector_type(4))) float f32x4;

__device__ inline unsigned short f2bf(float x) {
  unsigned u = __float_as_uint(x);
  unsigned rounding = 0x7FFFu + ((u >> 16) & 1u);
  return (unsigned short)((u + rounding) >> 16);
}
__device__ inline float bf2f(unsigned short u) {
  return __uint_as_float(((unsigned)u) << 16);
}
__device__ inline void gload_lds16(const void* g, void* l) {
  __builtin_amdgcn_global_load_lds(
      (const __attribute__((address_space(1))) unsigned int*)g,
      (__attribute__((address_space(3))) unsigned int*)l, 16, 0, 0);
}

#define KPAD 5440   // 5408 padded to 85*64
#define NPAD 4864   // 4800 padded to 38*128
#define X1Q  32768  // bytes per (pair, quarter) region in X1 (28800 used)
#define SBUF 14336  // conv2 per-quarter staging buffer (14 x 1KB calls max)

// ---------------------------------------------------------------------------
// Kernel 1: pair decode + rasterize + slicing output
// ---------------------------------------------------------------------------
__global__ void prep_pairs(const float* __restrict__ bboxes,
                           const int* __restrict__ num_obj, int M,
                           int* __restrict__ pairTab,
                           float* __restrict__ slicing) {
  __shared__ int cum[9];
  if (threadIdx.x == 0) {
    int c = 0; cum[0] = 0;
    for (int b = 0; b < 8; b++) { int n = num_obj[b]; c += n*(n-1)/2; cum[b+1] = c; }
  }
  __syncthreads();
  for (int m = threadIdx.x; m < M; m += blockDim.x) {
    int b = 0;
    while (b < 7 && m >= cum[b+1]) b++;
    int p = m - cum[b];
    int n = num_obj[b];
    int i = 0, rem = p;
    while (rem >= (n - 1 - i)) { rem -= (n - 1 - i); i++; }
    int j = i + 1 + rem;
    const float* A = bboxes + (b*24 + i)*4;
    const float* Bb = bboxes + (b*24 + j)*4;
    float ax1=A[0], ay1=A[1], ax2=A[2], ay2=A[3];
    float bx1=Bb[0], by1=Bb[1], bx2=Bb[2], by2=Bb[3];
    float u1 = fminf(ax1,bx1), v1 = fminf(ay1,by1);
    float u2 = fmaxf(ax2,bx2), v2 = fmaxf(ay2,by2);
    float w = u2-u1, h = v2-v1;
    float scale = 63.0f / fmaxf(fmaxf(w,h), 1e-6f);
    float offx = (h >= w) ? __fmul_rn(63.0f - __fmul_rn(w,scale), 0.5f) : 0.0f;
    float offy = (w > h)  ? __fmul_rn(63.0f - __fmul_rn(h,scale), 0.5f) : 0.0f;
    int* t = pairTab + m*8;
    t[0] = (int)rintf(__fadd_rn(__fmul_rn(ax1-u1, scale), offx));
    t[1] = (int)rintf(__fadd_rn(__fmul_rn(ay1-v1, scale), offy));
    t[2] = (int)rintf(__fadd_rn(__fmul_rn(ax2-u1, scale), offx));
    t[3] = (int)rintf(__fadd_rn(__fmul_rn(ay2-v1, scale), offy));
    t[4] = (int)rintf(__fadd_rn(__fmul_rn(bx1-u1, scale), offx));
    t[5] = (int)rintf(__fadd_rn(__fmul_rn(by1-v1, scale), offy));
    t[6] = (int)rintf(__fadd_rn(__fmul_rn(bx2-u1, scale), offx));
    t[7] = (int)rintf(__fadd_rn(__fmul_rn(by2-v1, scale), offy));
    slicing[m*3+0] = (float)b;
    slicing[m*3+1] = (float)i;
    slicing[m*3+2] = (float)j;
  }
}

// ---------------------------------------------------------------------------
// Kernel 2: conv1 range-sum table T[c][ry26][rx26][64] (+half conv1 bias in
// each of c=0/1) + conv2 weights reorder W2B (zero when kyx>=25, K padding)
// ---------------------------------------------------------------------------
__global__ void prep_tables(const float* __restrict__ w1, const float* __restrict__ b1,
                            const float* __restrict__ w2,
                            float* __restrict__ T, unsigned short* __restrict__ W2B) {
  int idx = blockIdx.x*256 + threadIdx.x;
  if (idx < 86528) {
    int o = idx & 63;
    int t = idx >> 6;
    int rxi = t % 26; t /= 26;
    int ryi = t % 26;
    int c = t / 26;
    int ky0 = ryi/5, ky1 = ryi%5, kx0 = rxi/5, kx1 = rxi%5;
    float s = 0.f;
    for (int ky = ky0; ky <= ky1; ky++)
      for (int kx = kx0; kx <= kx1; kx++)
        s += w1[((o*2 + c)*5 + ky)*5 + kx];
    T[idx] = s + 0.5f * b1[o];
  } else if (idx < 86528 + 53248) {
    int i = idx - 86528;
    int j = i & 7;
    int ln = (i >> 3) & 63;
    int r1 = i >> 9;
    int mt = r1 & 1;
    int r2 = r1 >> 1;
    int s = r2 % 13;
    int pp = r2 / 13;
    int oc = mt*16 + (ln & 15);
    int q = ln >> 4;
    int kyx = 2*s + (q >> 1);
    int ic = pp*16 + ((q & 1) << 3) + j;
    float val = 0.f;
    if (kyx < 25) val = w2[((oc*64 + ic)*5 + kyx/5)*5 + (kyx%5)];
    W2B[i] = f2bf(val);
  }
}

// ---------------------------------------------------------------------------
// Kernel 3: transpose+cast lin_w [5408][4800] f32 -> Wt [4800][KPAD] bf16
// ---------------------------------------------------------------------------
__global__ __launch_bounds__(256) void prep_wt(const float* __restrict__ lw,
                                               unsigned short* __restrict__ Wt) {
  __shared__ unsigned short tile[64][65];
  int k0 = blockIdx.x*64, n0 = blockIdx.y*64;
  for (int i = threadIdx.x; i < 64*64; i += 256) {
    int r = i >> 6, cdx = i & 63;
    int k = k0 + r, n = n0 + cdx;
    float v = (k < 5408) ? lw[(size_t)k*4800 + n] : 0.f;
    tile[r][cdx] = f2bf(v);
  }
  __syncthreads();
  for (int i = threadIdx.x; i < 64*64; i += 256) {
    int r = i >> 6, cdx = i & 63;
    int n = n0 + r, k = k0 + cdx;
    Wt[(size_t)n*KPAD + k] = tile[cdx][r];
  }
}

// ---------------------------------------------------------------------------
// Kernel 4a: conv1 (table lookup, bias folded) + relu + pool1.
// One block per (pair, quarter); 2160 blocks, 256 threads, no accumulator ->
// ~50 regs, full occupancy. Output X1 in LDS-linear SWIZZLED byte order so
// conv2 can stage it with plain linear global_load_lds.
// ---------------------------------------------------------------------------
__global__ __launch_bounds__(256) void conv1_pool(
    const int* __restrict__ pairTab, const float* __restrict__ T,
    unsigned short* __restrict__ X1) {
  __shared__ unsigned char rIdx[4][64];
  int blk = blockIdx.x;
  int m = blk >> 2, pp = blk & 3;
  int tid = threadIdx.x;
  const int* pt = pairTab + m*8;

  if (tid < 240) {
    int qq = tid % 60, which = tid / 60;
    int lo, hi;
    if (which == 0)      { lo = pt[1]; hi = pt[3]; }
    else if (which == 1) { lo = pt[5]; hi = pt[7]; }
    else if (which == 2) { lo = pt[0]; hi = pt[2]; }
    else                 { lo = pt[4]; hi = pt[6]; }
    int k0 = lo - qq; if (k0 < 0) k0 = 0;
    int k1 = hi - qq; if (k1 > 4) k1 = 4;
    rIdx[which][qq] = (k0 > k1) ? (unsigned char)25 : (unsigned char)(k0*5 + k1);
  }
  __syncthreads();

  char* X1q = (char*)X1 + (size_t)blk * X1Q;
  for (int item = tid; item < 1800; item += 256) {
    int pos = item >> 1;
    int icg = item & 1;
    int ch0 = pp*16 + icg*8;
    int py = pos / 30, px = pos % 30;
    float best[8];
#pragma unroll
    for (int j = 0; j < 8; j++) best[j] = -1e30f;
#pragma unroll
    for (int d = 0; d < 4; d++) {
      int y = py*2 + (d>>1), x = px*2 + (d&1);
      int rya = rIdx[0][y], ryb = rIdx[1][y];
      int rxa = rIdx[2][x], rxb = rIdx[3][x];
      const float* Ta = T + (((rya)*26 + rxa)<<6) + ch0;
      const float* Tb = T + (((26 + ryb)*26 + rxb)<<6) + ch0;
      f32x4 a0 = *(const f32x4*)Ta, a1 = *(const f32x4*)(Ta+4);
      f32x4 c0 = *(const f32x4*)Tb, c1 = *(const f32x4*)(Tb+4);
#pragma unroll
      for (int j = 0; j < 4; j++) {
        best[j]   = fmaxf(best[j],   a0[j]+c0[j]);
        best[4+j] = fmaxf(best[4+j], a1[j]+c1[j]);
      }
    }
    short8 v;
#pragma unroll
    for (int j = 0; j < 8; j++)
      v[j] = (short)f2bf(fmaxf(best[j], 0.f));
    int byte = pos*32 + ((icg ^ ((pos>>2)&1))<<4);
    *(short8*)(X1q + byte) = v;
  }
}

// ---------------------------------------------------------------------------
// Kernel 4b: conv2 via MFMA + pool2. One block per (pair, oy-THIRD):
// thirds cover pool rows 0-3 / 4-8 / 9-12 (oy 0-7 / 8-17 / 18-25) -> pool
// pairs never straddle. Grid 3M, 256 threads (4 waves), max 5 tiles/wave ->
// acc[5][2] = 40 acc regs, total VGPR ~120 <= 128 cliff (round-7 lesson:
// 132 regs halved occupancy). Staging 12-14KB/quarter, dbuf 28.7KB ->
// 4 blocks/CU (VGPR-limited), 16 waves/CU. NO min-wave launch_bounds.
// ---------------------------------------------------------------------------
__global__ __launch_bounds__(256) void conv2_mfma(
    const unsigned short* __restrict__ X1, const unsigned short* __restrict__ W2B,
    const float* __restrict__ b2, unsigned short* __restrict__ X, int M) {
  __shared__ char smem[2*SBUF];   // 28.7KB staging dbuf; stage3 reuses (16.6KB)
  int blk = blockIdx.x;
  int m = blk / 3, t = blk - m*3;
  int tid = threadIdx.x, lane = tid & 63, wid = tid >> 6;
  const char* X1m = (const char*)X1 + (size_t)m*4*X1Q;

  int oy0    = (t == 0) ? 0 : (t == 1 ? 8 : 18);
  int npos   = (t == 1) ? 260 : 208;
  int ntiles = (t == 1) ? 17 : 13;
  int row0   = oy0 * 30;                 // 0 / 240 / 540
  int ncall  = (t == 1) ? 14 : 12;       // 1KB gload_lds calls per quarter

  int tbase = ntiles >> 2, trem = ntiles & 3;
  int ntile  = tbase + (wid < trem ? 1 : 0);
  int tstart = (wid < trem) ? wid*(tbase+1) : trem*(tbase+1) + (wid-trem)*tbase;

  int rowbase[5];
#pragma unroll
  for (int tt = 0; tt < 5; tt++) {
    int pos = (tstart + tt)*16 + (lane & 15);
    if (pos > npos-1) pos = npos-1;
    int oy = oy0 + pos/26;
    rowbase[tt] = oy*30 + pos%26;
  }
  f32x4 acc[5][2];
#pragma unroll
  for (int tt = 0; tt < 5; tt++) {
    acc[tt][0] = (f32x4){0.f,0.f,0.f,0.f};
    acc[tt][1] = (f32x4){0.f,0.f,0.f,0.f};
  }

  int q = lane >> 4, qh = q >> 1, qs = q & 1;

  auto stageq = [&](int buf, int qtr) {
    const char* src = X1m + (size_t)qtr * X1Q + row0*32;
    char* dst = smem + buf * SBUF;
#pragma unroll
    for (int c = 0; c < 4; c++) {
      int chunk = wid + c*4;
      if (chunk < ncall)
        gload_lds16(src + chunk*1024 + lane*16, dst + chunk*1024);
    }
  };

  stageq(0, 0);
  __syncthreads();                          // drains vmcnt (gload_lds) too
  for (int pp = 0; pp < 4; pp++) {
    if (pp < 3) stageq((pp+1) & 1, pp+1);   // prefetch next quarter
    const char* pb = smem + (pp & 1) * SBUF;
    for (int s = 0; s < 13; s++) {
      const unsigned short* wptr = W2B + (size_t)(pp*13 + s)*1024 + lane*8;
      short8 a0 = *(const short8*)wptr;
      short8 a1 = *(const short8*)(wptr + 512);
      int kyx = 2*s + qh; if (kyx > 24) kyx = 24;
      int radd = (kyx/5)*30 + (kyx%5);
#pragma unroll
      for (int tt = 0; tt < 5; tt++) {
        if (tt < ntile) {
          int row = rowbase[tt] + radd;
          int byte = (row - row0)*32 + ((qs ^ ((row>>2)&1))<<4);
          short8 bv = *(const short8*)(pb + byte);
          acc[tt][0] = __builtin_amdgcn_mfma_f32_16x16x32_bf16(a0, bv, acc[tt][0], 0, 0, 0);
          acc[tt][1] = __builtin_amdgcn_mfma_f32_16x16x32_bf16(a1, bv, acc[tt][1], 0, 0, 0);
        }
      }
    }
    __syncthreads();
  }
  // stage3: dump conv2 (pre-bias) to LDS bf16 [32][npos]
  unsigned short* p1 = (unsigned short*)smem;
#pragma unroll
  for (int tt = 0; tt < 5; tt++) {
    if (tt < ntile) {
      int pos = (tstart + tt)*16 + (lane & 15);
      if (pos < npos) {
#pragma unroll
        for (int mt = 0; mt < 2; mt++)
#pragma unroll
          for (int r = 0; r < 4; r++) {
            int oc = mt*16 + q*4 + r;
            p1[oc*npos + pos] = f2bf(acc[tt][mt][r]);
          }
      }
    }
  }
  __syncthreads();
  // pool2 + bias + relu -> X[m][KPAD] bf16 (this third's pool rows only)
  int pr0  = (t == 0) ? 0 : (t == 1 ? 4 : 9);
  int nout = (t == 1) ? 5 : 4;
  for (int f = tid; f < 32*nout*13; f += 256) {
    int ocl = f / (nout*13), rem2 = f % (nout*13);
    int oyl = rem2 / 13, px = rem2 % 13;
    int oyp = pr0 + oyl;
    int posl = (oyp*2 - oy0)*26 + px*2;
    const unsigned short* c2 = p1 + ocl*npos + posl;
    float v = fmaxf(fmaxf(bf2f(c2[0]), bf2f(c2[1])), fmaxf(bf2f(c2[26]), bf2f(c2[27])));
    X[(size_t)m*KPAD + ocl*169 + oyp*13 + px] = f2bf(fmaxf(v + b2[ocl], 0.f));
  }
  if (t == 0 && tid < 32) X[(size_t)m*KPAD + 5408 + tid] = 0;
}

// ---------------------------------------------------------------------------
// Kernel 5: linear GEMM, split-K, 2-phase pipelined.
// BM=64, BN=128, BK=64, 4 waves (2x2), each wave 32x64.
// ---------------------------------------------------------------------------
__global__ __launch_bounds__(256) void gemm_lin(
    const unsigned short* __restrict__ X, const unsigned short* __restrict__ Wt,
    const float* __restrict__ lin_b, float* __restrict__ P, float* __restrict__ out,
    int M, int Mpad, int splits) {
  __shared__ unsigned short As[2][4096];   //  8KB x2: 64 rows x 64 k
  __shared__ unsigned short Bs[2][8192];   // 16KB x2: 128 rows x 64 k
  int tid = threadIdx.x, lane = tid & 63, wid = tid >> 6;
  int m0 = blockIdx.x * 64, n0 = blockIdx.y * 128;
  int ks = blockIdx.z;
  int itBeg = (ks * 85) / splits, itEnd = ((ks + 1) * 85) / splits;
  int wm = wid >> 1, wn = wid & 1;

  f32x4 acc[2][4];
#pragma unroll
  for (int i = 0; i < 2; i++)
#pragma unroll
    for (int j = 0; j < 4; j++) acc[i][j] = (f32x4){0.f,0.f,0.f,0.f};

  int rsub = lane >> 3;
  int kslot = (lane & 7) ^ rsub;
  int kg = lane >> 4;

  auto stage = [&](int buf, int it) {
    size_t kof = (size_t)it * 64 + kslot * 8;
#pragma unroll
    for (int cc = 0; cc < 2; cc++) {
      int chunk = wid + cc*4;
      int gm = m0 + chunk*8 + rsub;
      gload_lds16(X + (size_t)gm*KPAD + kof, (char*)As[buf] + chunk*1024);
    }
#pragma unroll
    for (int cc = 0; cc < 4; cc++) {
      int chunk = wid + cc*4;
      int gn = n0 + chunk*8 + rsub;
      gload_lds16(Wt + (size_t)gn*KPAD + kof, (char*)Bs[buf] + chunk*1024);
    }
  };

  stage(0, itBeg);
  __syncthreads();
  int cur = 0;
  for (int it = itBeg; it < itEnd; ++it) {
    if (it + 1 < itEnd) stage(cur ^ 1, it + 1);
#pragma unroll
    for (int ksub = 0; ksub < 2; ++ksub) {
      int slot = ksub*4 + kg;
      short8 af[2], bfr[4];
#pragma unroll
      for (int mf = 0; mf < 2; mf++) {
        int r = wm*32 + mf*16 + (lane & 15);
        af[mf] = *(const short8*)((const char*)As[cur] + r*128 + ((slot ^ (lane&7))<<4));
      }
#pragma unroll
      for (int nf = 0; nf < 4; nf++) {
        int r = wn*64 + nf*16 + (lane & 15);
        bfr[nf] = *(const short8*)((const char*)Bs[cur] + r*128 + ((slot ^ (lane&7))<<4));
      }
#pragma unroll
      for (int mf = 0; mf < 2; mf++)
#pragma unroll
        for (int nf = 0; nf < 4; nf++)
          acc[mf][nf] = __builtin_amdgcn_mfma_f32_16x16x32_bf16(af[mf], bfr[nf], acc[mf][nf], 0, 0, 0);
    }
    __syncthreads();
    cur ^= 1;
  }

  if (splits == 1) {
#pragma unroll
    for (int mf = 0; mf < 2; mf++)
#pragma unroll
      for (int nf = 0; nf < 4; nf++) {
        int n = n0 + wn*64 + nf*16 + (lane & 15);
#pragma unroll
        for (int r = 0; r < 4; r++) {
          int mm = m0 + wm*32 + mf*16 + ((lane>>4)<<2) + r;
          if (mm < M && n < 4800)
            out[(size_t)mm*4800 + n] = fmaxf(acc[mf][nf][r] + lin_b[n], 0.f);
        }
      }
  } else {
    float* Pp = P + (size_t)ks * Mpad * NPAD;
#pragma unroll
    for (int mf = 0; mf < 2; mf++)
#pragma unroll
      for (int nf = 0; nf < 4; nf++) {
        int n = n0 + wn*64 + nf*16 + (lane & 15);
#pragma unroll
        for (int r = 0; r < 4; r++) {
          int mm = m0 + wm*32 + mf*16 + ((lane>>4)<<2) + r;
          Pp[(size_t)mm*NPAD + n] = acc[mf][nf][r];
        }
      }
  }
}

// ---------------------------------------------------------------------------
// Kernel 6: split-K reduce + bias + relu
// ---------------------------------------------------------------------------
__global__ void reduce_out(const float* __restrict__ P, const float* __restrict__ lb,
                           float* __restrict__ out, int M, int Mpad, int splits) {
  int total = M * 1200;  // float4 granules
  for (int idx = blockIdx.x*256 + threadIdx.x; idx < total; idx += gridDim.x*256) {
    int m = idx / 1200, qq = idx - m*1200;
    int n = qq * 4;
    f32x4 s = *(const f32x4*)(P + (size_t)m*NPAD + n);
    for (int sidx = 1; sidx < splits; sidx++)
      s += *(const f32x4*)(P + (size_t)sidx*Mpad*NPAD + (size_t)m*NPAD + n);
    f32x4 b = *(const f32x4*)(lb + n);
    f32x4 r;
#pragma unroll
    for (int j = 0; j < 4; j++) r[j] = fmaxf(s[j] + b[j], 0.f);
    *(f32x4*)(out + (size_t)m*4800 + n) = r;
  }
}

// ---------------------------------------------------------------------------
extern "C" void kernel_launch(void* const* d_in, const int* in_sizes, int n_in,
                              void* d_out, int out_size, void* d_ws, size_t ws_size,
                              hipStream_t stream) {
  const float* bboxes = (const float*)d_in[0];
  const int*   num_obj = (const int*)d_in[1];
  const float* w1 = (const float*)d_in[2];
  const float* b1 = (const float*)d_in[3];
  const float* w2 = (const float*)d_in[4];
  const float* b2 = (const float*)d_in[5];
  const float* lw = (const float*)d_in[6];
  const float* lb = (const float*)d_in[7];
  float* out = (float*)d_out;
  int M = out_size / 4803;
  int Mpad = (M + 63) & ~63;

  auto align512 = [](size_t x) { return (x + 511) & ~(size_t)511; };
  size_t fixed = 0;
  fixed += align512((size_t)M*8*4);            // pairTab
  fixed += align512((size_t)86528*4);          // T
  fixed += align512((size_t)53248*2);          // W2B
  fixed += align512((size_t)4800*KPAD*2);      // Wt
  fixed += align512((size_t)Mpad*KPAD*2);      // X
  fixed += align512((size_t)M*4*X1Q);          // X1
  int splits = 4;
  while (splits > 1 && fixed + align512((size_t)splits*Mpad*NPAD*4) > ws_size) splits >>= 1;

  char* ws = (char*)d_ws;
  size_t off = 0;
  auto alloc = [&](size_t bytes) {
    off = align512(off);
    char* p = ws + off;
    off += bytes;
    return p;
  };
  int* pairTab = (int*)alloc((size_t)M*8*4);
  float* T = (float*)alloc((size_t)86528*4);
  unsigned short* W2B = (unsigned short*)alloc((size_t)53248*2);
  unsigned short* Wt = (unsigned short*)alloc((size_t)4800*KPAD*2);
  unsigned short* X = (unsigned short*)alloc((size_t)Mpad*KPAD*2);
  unsigned short* X1 = (unsigned short*)alloc((size_t)M*4*X1Q);
  float* P = (splits > 1) ? (float*)alloc((size_t)splits*Mpad*NPAD*4) : nullptr;

  prep_pairs<<<1, 256, 0, stream>>>(bboxes, num_obj, M, pairTab, out + (size_t)M*4800);
  prep_tables<<<(86528+53248+255)/256, 256, 0, stream>>>(w1, b1, w2, T, W2B);
  prep_wt<<<dim3(85, 75), 256, 0, stream>>>(lw, Wt);
  conv1_pool<<<M*4, 256, 0, stream>>>(pairTab, T, X1);
  conv2_mfma<<<M*3, 256, 0, stream>>>(X1, W2B, b2, X, M);
  gemm_lin<<<dim3(Mpad/64, 38, splits), 256, 0, stream>>>(X, Wt, lb, P, out, M, Mpad, splits);
  if (splits > 1)
    reduce_out<<<1024, 256, 0, stream>>>(P, lb, out, M, Mpad, splits);
}

// Round 9
// 339.976 us; speedup vs baseline: 1.1857x; 1.0387x over previous
//
#include <hip/hip_runtime.h>
#include <hip/hip_bf16.h>

typedef __attribute__((ext_vector_type(8))) short short8;
typedef __attribute__((ext_vector_type(4))) float f32x4;

__device__ inline unsigned short f2bf(float x) {
  unsigned u = __float_as_uint(x);
  unsigned rounding = 0x7FFFu + ((u >> 16) & 1u);
  return (unsigned short)((u + rounding) >> 16);
}
__device__ inline float bf2f(unsigned short u) {
  return __uint_as_float(((unsigned)u) << 16);
}
__device__ inline void gload_lds16(const void* g, void* l) {
  __builtin_amdgcn_global_load_lds(
      (const __attribute__((address_space(1))) unsigned int*)g,
      (__attribute__((address_space(3))) unsigned int*)l, 16, 0, 0);
}

#define KPAD 5440   // 5408 padded to 85*64
#define NPAD 4864   // 4800 padded to 38*128

// ---------------------------------------------------------------------------
// Kernel 1: pair decode + rasterize + slicing output
// ---------------------------------------------------------------------------
__global__ void prep_pairs(const float* __restrict__ bboxes,
                           const int* __restrict__ num_obj, int M,
                           int* __restrict__ pairTab,
                           float* __restrict__ slicing) {
  __shared__ int cum[9];
  if (threadIdx.x == 0) {
    int c = 0; cum[0] = 0;
    for (int b = 0; b < 8; b++) { int n = num_obj[b]; c += n*(n-1)/2; cum[b+1] = c; }
  }
  __syncthreads();
  for (int m = threadIdx.x; m < M; m += blockDim.x) {
    int b = 0;
    while (b < 7 && m >= cum[b+1]) b++;
    int p = m - cum[b];
    int n = num_obj[b];
    int i = 0, rem = p;
    while (rem >= (n - 1 - i)) { rem -= (n - 1 - i); i++; }
    int j = i + 1 + rem;
    const float* A = bboxes + (b*24 + i)*4;
    const float* Bb = bboxes + (b*24 + j)*4;
    float ax1=A[0], ay1=A[1], ax2=A[2], ay2=A[3];
    float bx1=Bb[0], by1=Bb[1], bx2=Bb[2], by2=Bb[3];
    float u1 = fminf(ax1,bx1), v1 = fminf(ay1,by1);
    float u2 = fmaxf(ax2,bx2), v2 = fmaxf(ay2,by2);
    float w = u2-u1, h = v2-v1;
    float scale = 63.0f / fmaxf(fmaxf(w,h), 1e-6f);
    float offx = (h >= w) ? __fmul_rn(63.0f - __fmul_rn(w,scale), 0.5f) : 0.0f;
    float offy = (w > h)  ? __fmul_rn(63.0f - __fmul_rn(h,scale), 0.5f) : 0.0f;
    int* t = pairTab + m*8;
    t[0] = (int)rintf(__fadd_rn(__fmul_rn(ax1-u1, scale), offx));
    t[1] = (int)rintf(__fadd_rn(__fmul_rn(ay1-v1, scale), offy));
    t[2] = (int)rintf(__fadd_rn(__fmul_rn(ax2-u1, scale), offx));
    t[3] = (int)rintf(__fadd_rn(__fmul_rn(ay2-v1, scale), offy));
    t[4] = (int)rintf(__fadd_rn(__fmul_rn(bx1-u1, scale), offx));
    t[5] = (int)rintf(__fadd_rn(__fmul_rn(by1-v1, scale), offy));
    t[6] = (int)rintf(__fadd_rn(__fmul_rn(bx2-u1, scale), offx));
    t[7] = (int)rintf(__fadd_rn(__fmul_rn(by2-v1, scale), offy));
    slicing[m*3+0] = (float)b;
    slicing[m*3+1] = (float)i;
    slicing[m*3+2] = (float)j;
  }
}

// ---------------------------------------------------------------------------
// Kernel 2: conv1 range-sum table T[c][ry26][rx26][64] (+half conv1 bias in
// each of c=0/1) + conv2 weights reorder W2B (zero when kyx>=25, K padding)
// ---------------------------------------------------------------------------
__global__ void prep_tables(const float* __restrict__ w1, const float* __restrict__ b1,
                            const float* __restrict__ w2,
                            float* __restrict__ T, unsigned short* __restrict__ W2B) {
  int idx = blockIdx.x*256 + threadIdx.x;
  if (idx < 86528) {
    int o = idx & 63;
    int t = idx >> 6;
    int rxi = t % 26; t /= 26;
    int ryi = t % 26;
    int c = t / 26;
    int ky0 = ryi/5, ky1 = ryi%5, kx0 = rxi/5, kx1 = rxi%5;
    float s = 0.f;
    for (int ky = ky0; ky <= ky1; ky++)
      for (int kx = kx0; kx <= kx1; kx++)
        s += w1[((o*2 + c)*5 + ky)*5 + kx];
    T[idx] = s + 0.5f * b1[o];
  } else if (idx < 86528 + 53248) {
    int i = idx - 86528;
    int j = i & 7;
    int ln = (i >> 3) & 63;
    int r1 = i >> 9;
    int mt = r1 & 1;
    int r2 = r1 >> 1;
    int s = r2 % 13;
    int pp = r2 / 13;
    int oc = mt*16 + (ln & 15);
    int q = ln >> 4;
    int kyx = 2*s + (q >> 1);
    int ic = pp*16 + ((q & 1) << 3) + j;
    float val = 0.f;
    if (kyx < 25) val = w2[((oc*64 + ic)*5 + kyx/5)*5 + (kyx%5)];
    W2B[i] = f2bf(val);
  }
}

// ---------------------------------------------------------------------------
// Kernel 3: transpose+cast lin_w [5408][4800] f32 -> Wt [4800][KPAD] bf16
// ---------------------------------------------------------------------------
__global__ __launch_bounds__(256) void prep_wt(const float* __restrict__ lw,
                                               unsigned short* __restrict__ Wt) {
  __shared__ unsigned short tile[64][65];
  int k0 = blockIdx.x*64, n0 = blockIdx.y*64;
  for (int i = threadIdx.x; i < 64*64; i += 256) {
    int r = i >> 6, cdx = i & 63;
    int k = k0 + r, n = n0 + cdx;
    float v = (k < 5408) ? lw[(size_t)k*4800 + n] : 0.f;
    tile[r][cdx] = f2bf(v);
  }
  __syncthreads();
  for (int i = threadIdx.x; i < 64*64; i += 256) {
    int r = i >> 6, cdx = i & 63;
    int n = n0 + r, k = k0 + cdx;
    Wt[(size_t)n*KPAD + k] = tile[cdx][r];
  }
}

// ---------------------------------------------------------------------------
// Kernel 4: FUSED conv1+pool1+conv2+pool2. One block per (pair, oy-third),
// 256 threads (4 waves). Rationale (rounds 2/6/8 evidence): split conv2 is
// latency-bound with homogeneous waves (125-134us at ANY occupancy 8-16
// waves/CU); fusing the VALU-heavy conv1 gather into the same kernel fills
// the MFMA/ds stall slots across co-resident blocks (m114) and deletes the
// 144MB X1 round-trip + a whole kernel.
// Per quarter (16 ch): stage1 computes pooled1 rows [row0/30, +NROWS) into
// LDS (13.4KB max, swizzled); stage2 runs 13 MFMA K-steps vs W2B from L2.
// acc[5][2]=40 AGPR; no min-wave launch_bounds (spill lesson, rounds 3-5).
// ---------------------------------------------------------------------------
__global__ __launch_bounds__(256) void pair_conv(
    const int* __restrict__ pairTab, const float* __restrict__ T,
    const unsigned short* __restrict__ W2B, const float* __restrict__ b2,
    unsigned short* __restrict__ X) {
  __shared__ char smem[17408];        // stage1/2: <=13.4KB; stage3: 32*260*2=16.6KB
  __shared__ unsigned char rIdx[4][64];
  int blk = blockIdx.x;
  int m = blk / 3, t = blk - m*3;
  int tid = threadIdx.x, lane = tid & 63, wid = tid >> 6;
  const int* pt = pairTab + m*8;

  if (tid < 240) {
    int qq = tid % 60, which = tid / 60;
    int lo, hi;
    if (which == 0)      { lo = pt[1]; hi = pt[3]; }
    else if (which == 1) { lo = pt[5]; hi = pt[7]; }
    else if (which == 2) { lo = pt[0]; hi = pt[2]; }
    else                 { lo = pt[4]; hi = pt[6]; }
    int k0 = lo - qq; if (k0 < 0) k0 = 0;
    int k1 = hi - qq; if (k1 > 4) k1 = 4;
    rIdx[which][qq] = (k0 > k1) ? (unsigned char)25 : (unsigned char)(k0*5 + k1);
  }

  int oy0    = (t == 0) ? 0 : (t == 1 ? 8 : 18);
  int npos   = (t == 1) ? 260 : 208;
  int ntiles = (t == 1) ? 17 : 13;
  int rstart = oy0;                        // first pooled1 row needed
  int NROWS  = (t == 1) ? 14 : 12;         // pooled1 rows incl. ky halo
  int row0   = rstart * 30;                // linear position base (mult of 4)
  int nitems = NROWS * 30 * 2;             // stage1 items (pos x 2 ch-chunks)

  int tbase = ntiles >> 2, trem = ntiles & 3;
  int ntile  = tbase + (wid < trem ? 1 : 0);
  int tstart = (wid < trem) ? wid*(tbase+1) : trem*(tbase+1) + (wid-trem)*tbase;

  int rowbase[5];
#pragma unroll
  for (int tt = 0; tt < 5; tt++) {
    int pos = (tstart + tt)*16 + (lane & 15);
    if (pos > npos-1) pos = npos-1;
    int oy = oy0 + pos/26;
    rowbase[tt] = oy*30 + pos%26;
  }
  f32x4 acc[5][2];
#pragma unroll
  for (int tt = 0; tt < 5; tt++) {
    acc[tt][0] = (f32x4){0.f,0.f,0.f,0.f};
    acc[tt][1] = (f32x4){0.f,0.f,0.f,0.f};
  }

  int q = lane >> 4, qh = q >> 1, qs = q & 1;

  for (int pp = 0; pp < 4; pp++) {
    __syncthreads();
    // ---- stage1: conv1 (table lookup, bias folded) + relu + pool1 -> LDS
    for (int item = tid; item < nitems; item += 256) {
      int pl = item >> 1;                  // local position 0..NROWS*30-1
      int icg = item & 1;
      int p = row0 + pl;                   // global linear position
      int ch0 = pp*16 + icg*8;
      int py = p / 30, px = p % 30;
      float best[8];
#pragma unroll
      for (int j = 0; j < 8; j++) best[j] = -1e30f;
#pragma unroll
      for (int d = 0; d < 4; d++) {
        int y = py*2 + (d>>1), x = px*2 + (d&1);
        int rya = rIdx[0][y], ryb = rIdx[1][y];
        int rxa = rIdx[2][x], rxb = rIdx[3][x];
        const float* Ta = T + (((rya)*26 + rxa)<<6) + ch0;
        const float* Tb = T + (((26 + ryb)*26 + rxb)<<6) + ch0;
        f32x4 a0 = *(const f32x4*)Ta, a1 = *(const f32x4*)(Ta+4);
        f32x4 c0 = *(const f32x4*)Tb, c1 = *(const f32x4*)(Tb+4);
#pragma unroll
        for (int j = 0; j < 4; j++) {
          best[j]   = fmaxf(best[j],   a0[j]+c0[j]);
          best[4+j] = fmaxf(best[4+j], a1[j]+c1[j]);
        }
      }
      short8 v;
#pragma unroll
      for (int j = 0; j < 8; j++)
        v[j] = (short)f2bf(fmaxf(best[j], 0.f));
      int byte = pl*32 + ((icg ^ ((p>>2)&1))<<4);
      *(short8*)(smem + byte) = v;
    }
    __syncthreads();
    // ---- stage2: conv2 partial over this 16-ch quarter (13 K-steps of 32)
    for (int s = 0; s < 13; s++) {
      const unsigned short* wptr = W2B + (size_t)(pp*13 + s)*1024 + lane*8;
      short8 a0 = *(const short8*)wptr;
      short8 a1 = *(const short8*)(wptr + 512);
      int kyx = 2*s + qh; if (kyx > 24) kyx = 24;
      int radd = (kyx/5)*30 + (kyx%5);
#pragma unroll
      for (int tt = 0; tt < 5; tt++) {
        if (tt < ntile) {
          int row = rowbase[tt] + radd;
          int byte = (row - row0)*32 + ((qs ^ ((row>>2)&1))<<4);
          short8 bv = *(const short8*)(smem + byte);
          acc[tt][0] = __builtin_amdgcn_mfma_f32_16x16x32_bf16(a0, bv, acc[tt][0], 0, 0, 0);
          acc[tt][1] = __builtin_amdgcn_mfma_f32_16x16x32_bf16(a1, bv, acc[tt][1], 0, 0, 0);
        }
      }
    }
  }
  __syncthreads();
  // ---- stage3: dump conv2 (pre-bias) to LDS bf16 [32][npos]
  unsigned short* p1 = (unsigned short*)smem;
#pragma unroll
  for (int tt = 0; tt < 5; tt++) {
    if (tt < ntile) {
      int pos = (tstart + tt)*16 + (lane & 15);
      if (pos < npos) {
#pragma unroll
        for (int mt = 0; mt < 2; mt++)
#pragma unroll
          for (int r = 0; r < 4; r++) {
            int oc = mt*16 + q*4 + r;
            p1[oc*npos + pos] = f2bf(acc[tt][mt][r]);
          }
      }
    }
  }
  __syncthreads();
  // ---- pool2 + bias + relu -> X[m][KPAD] bf16 (this third's pool rows)
  int pr0  = (t == 0) ? 0 : (t == 1 ? 4 : 9);
  int nout = (t == 1) ? 5 : 4;
  for (int f = tid; f < 32*nout*13; f += 256) {
    int ocl = f / (nout*13), rem2 = f % (nout*13);
    int oyl = rem2 / 13, px = rem2 % 13;
    int oyp = pr0 + oyl;
    int posl = (oyp*2 - oy0)*26 + px*2;
    const unsigned short* c2 = p1 + ocl*npos + posl;
    float v = fmaxf(fmaxf(bf2f(c2[0]), bf2f(c2[1])), fmaxf(bf2f(c2[26]), bf2f(c2[27])));
    X[(size_t)m*KPAD + ocl*169 + oyp*13 + px] = f2bf(fmaxf(v + b2[ocl], 0.f));
  }
  if (t == 0 && tid < 32) X[(size_t)m*KPAD + 5408 + tid] = 0;
}

// ---------------------------------------------------------------------------
// Kernel 5: linear GEMM, split-K, 2-phase pipelined.
// BM=64, BN=128, BK=64, 4 waves (2x2), each wave 32x64.
// ---------------------------------------------------------------------------
__global__ __launch_bounds__(256) void gemm_lin(
    const unsigned short* __restrict__ X, const unsigned short* __restrict__ Wt,
    const float* __restrict__ lin_b, float* __restrict__ P, float* __restrict__ out,
    int M, int Mpad, int splits) {
  __shared__ unsigned short As[2][4096];   //  8KB x2: 64 rows x 64 k
  __shared__ unsigned short Bs[2][8192];   // 16KB x2: 128 rows x 64 k
  int tid = threadIdx.x, lane = tid & 63, wid = tid >> 6;
  int m0 = blockIdx.x * 64, n0 = blockIdx.y * 128;
  int ks = blockIdx.z;
  int itBeg = (ks * 85) / splits, itEnd = ((ks + 1) * 85) / splits;
  int wm = wid >> 1, wn = wid & 1;

  f32x4 acc[2][4];
#pragma unroll
  for (int i = 0; i < 2; i++)
#pragma unroll
    for (int j = 0; j < 4; j++) acc[i][j] = (f32x4){0.f,0.f,0.f,0.f};

  int rsub = lane >> 3;
  int kslot = (lane & 7) ^ rsub;
  int kg = lane >> 4;

  auto stage = [&](int buf, int it) {
    size_t kof = (size_t)it * 64 + kslot * 8;
#pragma unroll
    for (int cc = 0; cc < 2; cc++) {
      int chunk = wid + cc*4;
      int gm = m0 + chunk*8 + rsub;
      gload_lds16(X + (size_t)gm*KPAD + kof, (char*)As[buf] + chunk*1024);
    }
#pragma unroll
    for (int cc = 0; cc < 4; cc++) {
      int chunk = wid + cc*4;
      int gn = n0 + chunk*8 + rsub;
      gload_lds16(Wt + (size_t)gn*KPAD + kof, (char*)Bs[buf] + chunk*1024);
    }
  };

  stage(0, itBeg);
  __syncthreads();
  int cur = 0;
  for (int it = itBeg; it < itEnd; ++it) {
    if (it + 1 < itEnd) stage(cur ^ 1, it + 1);
#pragma unroll
    for (int ksub = 0; ksub < 2; ++ksub) {
      int slot = ksub*4 + kg;
      short8 af[2], bfr[4];
#pragma unroll
      for (int mf = 0; mf < 2; mf++) {
        int r = wm*32 + mf*16 + (lane & 15);
        af[mf] = *(const short8*)((const char*)As[cur] + r*128 + ((slot ^ (lane&7))<<4));
      }
#pragma unroll
      for (int nf = 0; nf < 4; nf++) {
        int r = wn*64 + nf*16 + (lane & 15);
        bfr[nf] = *(const short8*)((const char*)Bs[cur] + r*128 + ((slot ^ (lane&7))<<4));
      }
#pragma unroll
      for (int mf = 0; mf < 2; mf++)
#pragma unroll
        for (int nf = 0; nf < 4; nf++)
          acc[mf][nf] = __builtin_amdgcn_mfma_f32_16x16x32_bf16(af[mf], bfr[nf], acc[mf][nf], 0, 0, 0);
    }
    __syncthreads();
    cur ^= 1;
  }

  if (splits == 1) {
#pragma unroll
    for (int mf = 0; mf < 2; mf++)
#pragma unroll
      for (int nf = 0; nf < 4; nf++) {
        int n = n0 + wn*64 + nf*16 + (lane & 15);
#pragma unroll
        for (int r = 0; r < 4; r++) {
          int mm = m0 + wm*32 + mf*16 + ((lane>>4)<<2) + r;
          if (mm < M && n < 4800)
            out[(size_t)mm*4800 + n] = fmaxf(acc[mf][nf][r] + lin_b[n], 0.f);
        }
      }
  } else {
    float* Pp = P + (size_t)ks * Mpad * NPAD;
#pragma unroll
    for (int mf = 0; mf < 2; mf++)
#pragma unroll
      for (int nf = 0; nf < 4; nf++) {
        int n = n0 + wn*64 + nf*16 + (lane & 15);
#pragma unroll
        for (int r = 0; r < 4; r++) {
          int mm = m0 + wm*32 + mf*16 + ((lane>>4)<<2) + r;
          Pp[(size_t)mm*NPAD + n] = acc[mf][nf][r];
        }
      }
  }
}

// ---------------------------------------------------------------------------
// Kernel 6: split-K reduce + bias + relu
// ---------------------------------------------------------------------------
__global__ void reduce_out(const float* __restrict__ P, const float* __restrict__ lb,
                           float* __restrict__ out, int M, int Mpad, int splits) {
  int total = M * 1200;  // float4 granules
  for (int idx = blockIdx.x*256 + threadIdx.x; idx < total; idx += gridDim.x*256) {
    int m = idx / 1200, qq = idx - m*1200;
    int n = qq * 4;
    f32x4 s = *(const f32x4*)(P + (size_t)m*NPAD + n);
    for (int sidx = 1; sidx < splits; sidx++)
      s += *(const f32x4*)(P + (size_t)sidx*Mpad*NPAD + (size_t)m*NPAD + n);
    f32x4 b = *(const f32x4*)(lb + n);
    f32x4 r;
#pragma unroll
    for (int j = 0; j < 4; j++) r[j] = fmaxf(s[j] + b[j], 0.f);
    *(f32x4*)(out + (size_t)m*4800 + n) = r;
  }
}

// ---------------------------------------------------------------------------
extern "C" void kernel_launch(void* const* d_in, const int* in_sizes, int n_in,
                              void* d_out, int out_size, void* d_ws, size_t ws_size,
                              hipStream_t stream) {
  const float* bboxes = (const float*)d_in[0];
  const int*   num_obj = (const int*)d_in[1];
  const float* w1 = (const float*)d_in[2];
  const float* b1 = (const float*)d_in[3];
  const float* w2 = (const float*)d_in[4];
  const float* b2 = (const float*)d_in[5];
  const float* lw = (const float*)d_in[6];
  const float* lb = (const float*)d_in[7];
  float* out = (float*)d_out;
  int M = out_size / 4803;
  int Mpad = (M + 63) & ~63;

  auto align512 = [](size_t x) { return (x + 511) & ~(size_t)511; };
  size_t fixed = 0;
  fixed += align512((size_t)M*8*4);            // pairTab
  fixed += align512((size_t)86528*4);          // T
  fixed += align512((size_t)53248*2);          // W2B
  fixed += align512((size_t)4800*KPAD*2);      // Wt
  fixed += align512((size_t)Mpad*KPAD*2);      // X
  int splits = 4;
  while (splits > 1 && fixed + align512((size_t)splits*Mpad*NPAD*4) > ws_size) splits >>= 1;

  char* ws = (char*)d_ws;
  size_t off = 0;
  auto alloc = [&](size_t bytes) {
    off = align512(off);
    char* p = ws + off;
    off += bytes;
    return p;
  };
  int* pairTab = (int*)alloc((size_t)M*8*4);
  float* T = (float*)alloc((size_t)86528*4);
  unsigned short* W2B = (unsigned short*)alloc((size_t)53248*2);
  unsigned short* Wt = (unsigned short*)alloc((size_t)4800*KPAD*2);
  unsigned short* X = (unsigned short*)alloc((size_t)Mpad*KPAD*2);
  float* P = (splits > 1) ? (float*)alloc((size_t)splits*Mpad*NPAD*4) : nullptr;

  prep_pairs<<<1, 256, 0, stream>>>(bboxes, num_obj, M, pairTab, out + (size_t)M*4800);
  prep_tables<<<(86528+53248+255)/256, 256, 0, stream>>>(w1, b1, w2, T, W2B);
  prep_wt<<<dim3(85, 75), 256, 0, stream>>>(lw, Wt);
  pair_conv<<<M*3, 256, 0, stream>>>(pairTab, T, W2B, b2, X);
  gemm_lin<<<dim3(Mpad/64, 38, splits), 256, 0, stream>>>(X, Wt, lb, P, out, M, Mpad, splits);
  if (splits > 1)
    reduce_out<<<1024, 256, 0, stream>>>(P, lb, out, M, Mpad, splits);
}

// Round 10
// 338.882 us; speedup vs baseline: 1.1896x; 1.0032x over previous
//
#include <hip/hip_runtime.h>
#include <hip/hip_bf16.h>

typedef __attribute__((ext_vector_type(8))) short short8;
typedef __attribute__((ext_vector_type(4))) float f32x4;

__device__ inline unsigned short f2bf(float x) {
  unsigned u = __float_as_uint(x);
  unsigned rounding = 0x7FFFu + ((u >> 16) & 1u);
  return (unsigned short)((u + rounding) >> 16);
}
__device__ inline float bf2f(unsigned short u) {
  return __uint_as_float(((unsigned)u) << 16);
}
__device__ inline void gload_lds16(const void* g, void* l) {
  __builtin_amdgcn_global_load_lds(
      (const __attribute__((address_space(1))) unsigned int*)g,
      (__attribute__((address_space(3))) unsigned int*)l, 16, 0, 0);
}

#define KPAD 5440   // 5408 padded to 85*64
#define NPAD 4864   // 4800 padded to 38*128
#define RSTRIDE 48  // pooled1 LDS row stride in bytes (16ch*2B + 16B pad):
                    // bank start (12*row)%32 has period 8 -> 16 consecutive
                    // rows cover all eight 4-bank windows 2x = conflict-free
#define QBUF (14*30*RSTRIDE)   // 20160B per pooled1 buffer (max NROWS=14)

// ---------------------------------------------------------------------------
// Kernel 1: pair decode + rasterize + slicing output
// ---------------------------------------------------------------------------
__global__ void prep_pairs(const float* __restrict__ bboxes,
                           const int* __restrict__ num_obj, int M,
                           int* __restrict__ pairTab,
                           float* __restrict__ slicing) {
  __shared__ int cum[9];
  if (threadIdx.x == 0) {
    int c = 0; cum[0] = 0;
    for (int b = 0; b < 8; b++) { int n = num_obj[b]; c += n*(n-1)/2; cum[b+1] = c; }
  }
  __syncthreads();
  for (int m = threadIdx.x; m < M; m += blockDim.x) {
    int b = 0;
    while (b < 7 && m >= cum[b+1]) b++;
    int p = m - cum[b];
    int n = num_obj[b];
    int i = 0, rem = p;
    while (rem >= (n - 1 - i)) { rem -= (n - 1 - i); i++; }
    int j = i + 1 + rem;
    const float* A = bboxes + (b*24 + i)*4;
    const float* Bb = bboxes + (b*24 + j)*4;
    float ax1=A[0], ay1=A[1], ax2=A[2], ay2=A[3];
    float bx1=Bb[0], by1=Bb[1], bx2=Bb[2], by2=Bb[3];
    float u1 = fminf(ax1,bx1), v1 = fminf(ay1,by1);
    float u2 = fmaxf(ax2,bx2), v2 = fmaxf(ay2,by2);
    float w = u2-u1, h = v2-v1;
    float scale = 63.0f / fmaxf(fmaxf(w,h), 1e-6f);
    float offx = (h >= w) ? __fmul_rn(63.0f - __fmul_rn(w,scale), 0.5f) : 0.0f;
    float offy = (w > h)  ? __fmul_rn(63.0f - __fmul_rn(h,scale), 0.5f) : 0.0f;
    int* t = pairTab + m*8;
    t[0] = (int)rintf(__fadd_rn(__fmul_rn(ax1-u1, scale), offx));
    t[1] = (int)rintf(__fadd_rn(__fmul_rn(ay1-v1, scale), offy));
    t[2] = (int)rintf(__fadd_rn(__fmul_rn(ax2-u1, scale), offx));
    t[3] = (int)rintf(__fadd_rn(__fmul_rn(ay2-v1, scale), offy));
    t[4] = (int)rintf(__fadd_rn(__fmul_rn(bx1-u1, scale), offx));
    t[5] = (int)rintf(__fadd_rn(__fmul_rn(by1-v1, scale), offy));
    t[6] = (int)rintf(__fadd_rn(__fmul_rn(bx2-u1, scale), offx));
    t[7] = (int)rintf(__fadd_rn(__fmul_rn(by2-v1, scale), offy));
    slicing[m*3+0] = (float)b;
    slicing[m*3+1] = (float)i;
    slicing[m*3+2] = (float)j;
  }
}

// ---------------------------------------------------------------------------
// Kernel 2: conv1 range-sum table T[c][ry26][rx26][64] (+half conv1 bias in
// each of c=0/1) + conv2 weights reorder W2B (zero when kyx>=25, K padding)
// ---------------------------------------------------------------------------
__global__ void prep_tables(const float* __restrict__ w1, const float* __restrict__ b1,
                            const float* __restrict__ w2,
                            float* __restrict__ T, unsigned short* __restrict__ W2B) {
  int idx = blockIdx.x*256 + threadIdx.x;
  if (idx < 86528) {
    int o = idx & 63;
    int t = idx >> 6;
    int rxi = t % 26; t /= 26;
    int ryi = t % 26;
    int c = t / 26;
    int ky0 = ryi/5, ky1 = ryi%5, kx0 = rxi/5, kx1 = rxi%5;
    float s = 0.f;
    for (int ky = ky0; ky <= ky1; ky++)
      for (int kx = kx0; kx <= kx1; kx++)
        s += w1[((o*2 + c)*5 + ky)*5 + kx];
    T[idx] = s + 0.5f * b1[o];
  } else if (idx < 86528 + 53248) {
    int i = idx - 86528;
    int j = i & 7;
    int ln = (i >> 3) & 63;
    int r1 = i >> 9;
    int mt = r1 & 1;
    int r2 = r1 >> 1;
    int s = r2 % 13;
    int pp = r2 / 13;
    int oc = mt*16 + (ln & 15);
    int q = ln >> 4;
    int kyx = 2*s + (q >> 1);
    int ic = pp*16 + ((q & 1) << 3) + j;
    float val = 0.f;
    if (kyx < 25) val = w2[((oc*64 + ic)*5 + kyx/5)*5 + (kyx%5)];
    W2B[i] = f2bf(val);
  }
}

// ---------------------------------------------------------------------------
// Kernel 3: transpose+cast lin_w [5408][4800] f32 -> Wt [4800][KPAD] bf16
// ---------------------------------------------------------------------------
__global__ __launch_bounds__(256) void prep_wt(const float* __restrict__ lw,
                                               unsigned short* __restrict__ Wt) {
  __shared__ unsigned short tile[64][65];
  int k0 = blockIdx.x*64, n0 = blockIdx.y*64;
  for (int i = threadIdx.x; i < 64*64; i += 256) {
    int r = i >> 6, cdx = i & 63;
    int k = k0 + r, n = n0 + cdx;
    float v = (k < 5408) ? lw[(size_t)k*4800 + n] : 0.f;
    tile[r][cdx] = f2bf(v);
  }
  __syncthreads();
  for (int i = threadIdx.x; i < 64*64; i += 256) {
    int r = i >> 6, cdx = i & 63;
    int n = n0 + r, k = k0 + cdx;
    Wt[(size_t)n*KPAD + k] = tile[cdx][r];
  }
}

// ---------------------------------------------------------------------------
// Kernel 4: FUSED conv1+pool1+conv2+pool2. One block per (pair, oy-third),
// 256 threads (4 waves).
// Round-10 changes vs round 9 (which was 198us, MfmaUtil 15 / VALUBusy 32 /
// occ 21 -- latency-bound, nothing saturated):
//  (a) RSTRIDE 32->48B kills the 4-way ds_read bank conflict (5.36M counts,
//      ~3.2 extra cyc per stage2 read).
//  (b) pooled1 double-buffer + ONE barrier per quarter: each wave runs
//      stage2(pp) then immediately stage1(pp+1) -> waves desync, conv1
//      VALU gathers fill conv2 MFMA/LDS stall slots (m114 co-issue).
// acc[5][2]=40 AGPR; no min-wave launch_bounds (rounds 3-5 spill lesson).
// ---------------------------------------------------------------------------
__global__ __launch_bounds__(256) void pair_conv(
    const int* __restrict__ pairTab, const float* __restrict__ T,
    const unsigned short* __restrict__ W2B, const float* __restrict__ b2,
    unsigned short* __restrict__ X) {
  __shared__ char smem[2*QBUF];       // 40.3KB dbuf; stage3 reuses first 16.6KB
  __shared__ unsigned char rIdx[4][64];
  int blk = blockIdx.x;
  int m = blk / 3, t = blk - m*3;
  int tid = threadIdx.x, lane = tid & 63, wid = tid >> 6;
  const int* pt = pairTab + m*8;

  if (tid < 240) {
    int qq = tid % 60, which = tid / 60;
    int lo, hi;
    if (which == 0)      { lo = pt[1]; hi = pt[3]; }
    else if (which == 1) { lo = pt[5]; hi = pt[7]; }
    else if (which == 2) { lo = pt[0]; hi = pt[2]; }
    else                 { lo = pt[4]; hi = pt[6]; }
    int k0 = lo - qq; if (k0 < 0) k0 = 0;
    int k1 = hi - qq; if (k1 > 4) k1 = 4;
    rIdx[which][qq] = (k0 > k1) ? (unsigned char)25 : (unsigned char)(k0*5 + k1);
  }

  int oy0    = (t == 0) ? 0 : (t == 1 ? 8 : 18);
  int npos   = (t == 1) ? 260 : 208;
  int ntiles = (t == 1) ? 17 : 13;
  int NROWS  = (t == 1) ? 14 : 12;         // pooled1 rows incl. ky halo
  int row0   = oy0 * 30;                   // linear position base
  int nitems = NROWS * 30 * 2;             // stage1 items (pos x 2 ch-chunks)

  int tbase = ntiles >> 2, trem = ntiles & 3;
  int ntile  = tbase + (wid < trem ? 1 : 0);
  int tstart = (wid < trem) ? wid*(tbase+1) : trem*(tbase+1) + (wid-trem)*tbase;

  int rowbase[5];
#pragma unroll
  for (int tt = 0; tt < 5; tt++) {
    int pos = (tstart + tt)*16 + (lane & 15);
    if (pos > npos-1) pos = npos-1;
    int oy = oy0 + pos/26;
    rowbase[tt] = oy*30 + pos%26;
  }
  f32x4 acc[5][2];
#pragma unroll
  for (int tt = 0; tt < 5; tt++) {
    acc[tt][0] = (f32x4){0.f,0.f,0.f,0.f};
    acc[tt][1] = (f32x4){0.f,0.f,0.f,0.f};
  }

  int q = lane >> 4, qh = q >> 1, qs = q & 1;

  // stage1: conv1 (table lookup, bias folded) + relu + pool1 for quarter pp
  auto stage1 = [&](int pp) {
    char* buf = smem + (pp & 1) * QBUF;
    for (int item = tid; item < nitems; item += 256) {
      int pl = item >> 1;                  // local position 0..NROWS*30-1
      int icg = item & 1;
      int p = row0 + pl;                   // global linear position
      int ch0 = pp*16 + icg*8;
      int py = p / 30, px = p % 30;
      float best[8];
#pragma unroll
      for (int j = 0; j < 8; j++) best[j] = -1e30f;
#pragma unroll
      for (int d = 0; d < 4; d++) {
        int y = py*2 + (d>>1), x = px*2 + (d&1);
        int rya = rIdx[0][y], ryb = rIdx[1][y];
        int rxa = rIdx[2][x], rxb = rIdx[3][x];
        const float* Ta = T + (((rya)*26 + rxa)<<6) + ch0;
        const float* Tb = T + (((26 + ryb)*26 + rxb)<<6) + ch0;
        f32x4 a0 = *(const f32x4*)Ta, a1 = *(const f32x4*)(Ta+4);
        f32x4 c0 = *(const f32x4*)Tb, c1 = *(const f32x4*)(Tb+4);
#pragma unroll
        for (int j = 0; j < 4; j++) {
          best[j]   = fmaxf(best[j],   a0[j]+c0[j]);
          best[4+j] = fmaxf(best[4+j], a1[j]+c1[j]);
        }
      }
      short8 v;
#pragma unroll
      for (int j = 0; j < 8; j++)
        v[j] = (short)f2bf(fmaxf(best[j], 0.f));
      *(short8*)(buf + pl*RSTRIDE + (icg<<4)) = v;
    }
  };

  __syncthreads();              // rIdx ready
  stage1(0);
  __syncthreads();              // buf0 ready

  for (int pp = 0; pp < 4; pp++) {
    const char* pb = smem + (pp & 1) * QBUF;
    // ---- stage2: conv2 partial over this 16-ch quarter (13 K-steps of 32)
    for (int s = 0; s < 13; s++) {
      const unsigned short* wptr = W2B + (size_t)(pp*13 + s)*1024 + lane*8;
      short8 a0 = *(const short8*)wptr;
      short8 a1 = *(const short8*)(wptr + 512);
      int kyx = 2*s + qh; if (kyx > 24) kyx = 24;
      int radd = (kyx/5)*30 + (kyx%5);
#pragma unroll
      for (int tt = 0; tt < 5; tt++) {
        if (tt < ntile) {
          int row = rowbase[tt] + radd;
          short8 bv = *(const short8*)(pb + (row - row0)*RSTRIDE + (qs<<4));
          acc[tt][0] = __builtin_amdgcn_mfma_f32_16x16x32_bf16(a0, bv, acc[tt][0], 0, 0, 0);
          acc[tt][1] = __builtin_amdgcn_mfma_f32_16x16x32_bf16(a1, bv, acc[tt][1], 0, 0, 0);
        }
      }
    }
    // ---- stage1 of next quarter into the other buffer (no barrier before:
    // different buffer; waves overlap VALU gathers with other waves' MFMAs)
    if (pp < 3) stage1(pp + 1);
    __syncthreads();
  }

  // ---- stage3: dump conv2 (pre-bias) to LDS bf16 [32][npos]
  unsigned short* p1 = (unsigned short*)smem;
#pragma unroll
  for (int tt = 0; tt < 5; tt++) {
    if (tt < ntile) {
      int pos = (tstart + tt)*16 + (lane & 15);
      if (pos < npos) {
#pragma unroll
        for (int mt = 0; mt < 2; mt++)
#pragma unroll
          for (int r = 0; r < 4; r++) {
            int oc = mt*16 + q*4 + r;
            p1[oc*npos + pos] = f2bf(acc[tt][mt][r]);
          }
      }
    }
  }
  __syncthreads();
  // ---- pool2 + bias + relu -> X[m][KPAD] bf16 (this third's pool rows)
  int pr0  = (t == 0) ? 0 : (t == 1 ? 4 : 9);
  int nout = (t == 1) ? 5 : 4;
  for (int f = tid; f < 32*nout*13; f += 256) {
    int ocl = f / (nout*13), rem2 = f % (nout*13);
    int oyl = rem2 / 13, px = rem2 % 13;
    int oyp = pr0 + oyl;
    int posl = (oyp*2 - oy0)*26 + px*2;
    const unsigned short* c2 = p1 + ocl*npos + posl;
    float v = fmaxf(fmaxf(bf2f(c2[0]), bf2f(c2[1])), fmaxf(bf2f(c2[26]), bf2f(c2[27])));
    X[(size_t)m*KPAD + ocl*169 + oyp*13 + px] = f2bf(fmaxf(v + b2[ocl], 0.f));
  }
  if (t == 0 && tid < 32) X[(size_t)m*KPAD + 5408 + tid] = 0;
}

// ---------------------------------------------------------------------------
// Kernel 5: linear GEMM, split-K, 2-phase pipelined.
// BM=64, BN=128, BK=64, 4 waves (2x2), each wave 32x64.
// ---------------------------------------------------------------------------
__global__ __launch_bounds__(256) void gemm_lin(
    const unsigned short* __restrict__ X, const unsigned short* __restrict__ Wt,
    const float* __restrict__ lin_b, float* __restrict__ P, float* __restrict__ out,
    int M, int Mpad, int splits) {
  __shared__ unsigned short As[2][4096];   //  8KB x2: 64 rows x 64 k
  __shared__ unsigned short Bs[2][8192];   // 16KB x2: 128 rows x 64 k
  int tid = threadIdx.x, lane = tid & 63, wid = tid >> 6;
  int m0 = blockIdx.x * 64, n0 = blockIdx.y * 128;
  int ks = blockIdx.z;
  int itBeg = (ks * 85) / splits, itEnd = ((ks + 1) * 85) / splits;
  int wm = wid >> 1, wn = wid & 1;

  f32x4 acc[2][4];
#pragma unroll
  for (int i = 0; i < 2; i++)
#pragma unroll
    for (int j = 0; j < 4; j++) acc[i][j] = (f32x4){0.f,0.f,0.f,0.f};

  int rsub = lane >> 3;
  int kslot = (lane & 7) ^ rsub;
  int kg = lane >> 4;

  auto stage = [&](int buf, int it) {
    size_t kof = (size_t)it * 64 + kslot * 8;
#pragma unroll
    for (int cc = 0; cc < 2; cc++) {
      int chunk = wid + cc*4;
      int gm = m0 + chunk*8 + rsub;
      gload_lds16(X + (size_t)gm*KPAD + kof, (char*)As[buf] + chunk*1024);
    }
#pragma unroll
    for (int cc = 0; cc < 4; cc++) {
      int chunk = wid + cc*4;
      int gn = n0 + chunk*8 + rsub;
      gload_lds16(Wt + (size_t)gn*KPAD + kof, (char*)Bs[buf] + chunk*1024);
    }
  };

  stage(0, itBeg);
  __syncthreads();
  int cur = 0;
  for (int it = itBeg; it < itEnd; ++it) {
    if (it + 1 < itEnd) stage(cur ^ 1, it + 1);
#pragma unroll
    for (int ksub = 0; ksub < 2; ++ksub) {
      int slot = ksub*4 + kg;
      short8 af[2], bfr[4];
#pragma unroll
      for (int mf = 0; mf < 2; mf++) {
        int r = wm*32 + mf*16 + (lane & 15);
        af[mf] = *(const short8*)((const char*)As[cur] + r*128 + ((slot ^ (lane&7))<<4));
      }
#pragma unroll
      for (int nf = 0; nf < 4; nf++) {
        int r = wn*64 + nf*16 + (lane & 15);
        bfr[nf] = *(const short8*)((const char*)Bs[cur] + r*128 + ((slot ^ (lane&7))<<4));
      }
#pragma unroll
      for (int mf = 0; mf < 2; mf++)
#pragma unroll
        for (int nf = 0; nf < 4; nf++)
          acc[mf][nf] = __builtin_amdgcn_mfma_f32_16x16x32_bf16(af[mf], bfr[nf], acc[mf][nf], 0, 0, 0);
    }
    __syncthreads();
    cur ^= 1;
  }

  if (splits == 1) {
#pragma unroll
    for (int mf = 0; mf < 2; mf++)
#pragma unroll
      for (int nf = 0; nf < 4; nf++) {
        int n = n0 + wn*64 + nf*16 + (lane & 15);
#pragma unroll
        for (int r = 0; r < 4; r++) {
          int mm = m0 + wm*32 + mf*16 + ((lane>>4)<<2) + r;
          if (mm < M && n < 4800)
            out[(size_t)mm*4800 + n] = fmaxf(acc[mf][nf][r] + lin_b[n], 0.f);
        }
      }
  } else {
    float* Pp = P + (size_t)ks * Mpad * NPAD;
#pragma unroll
    for (int mf = 0; mf < 2; mf++)
#pragma unroll
      for (int nf = 0; nf < 4; nf++) {
        int n = n0 + wn*64 + nf*16 + (lane & 15);
#pragma unroll
        for (int r = 0; r < 4; r++) {
          int mm = m0 + wm*32 + mf*16 + ((lane>>4)<<2) + r;
          Pp[(size_t)mm*NPAD + n] = acc[mf][nf][r];
        }
      }
  }
}

// ---------------------------------------------------------------------------
// Kernel 6: split-K reduce + bias + relu
// ---------------------------------------------------------------------------
__global__ void reduce_out(const float* __restrict__ P, const float* __restrict__ lb,
                           float* __restrict__ out, int M, int Mpad, int splits) {
  int total = M * 1200;  // float4 granules
  for (int idx = blockIdx.x*256 + threadIdx.x; idx < total; idx += gridDim.x*256) {
    int m = idx / 1200, qq = idx - m*1200;
    int n = qq * 4;
    f32x4 s = *(const f32x4*)(P + (size_t)m*NPAD + n);
    for (int sidx = 1; sidx < splits; sidx++)
      s += *(const f32x4*)(P + (size_t)sidx*Mpad*NPAD + (size_t)m*NPAD + n);
    f32x4 b = *(const f32x4*)(lb + n);
    f32x4 r;
#pragma unroll
    for (int j = 0; j < 4; j++) r[j] = fmaxf(s[j] + b[j], 0.f);
    *(f32x4*)(out + (size_t)m*4800 + n) = r;
  }
}

// ---------------------------------------------------------------------------
extern "C" void kernel_launch(void* const* d_in, const int* in_sizes, int n_in,
                              void* d_out, int out_size, void* d_ws, size_t ws_size,
                              hipStream_t stream) {
  const float* bboxes = (const float*)d_in[0];
  const int*   num_obj = (const int*)d_in[1];
  const float* w1 = (const float*)d_in[2];
  const float* b1 = (const float*)d_in[3];
  const float* w2 = (const float*)d_in[4];
  const float* b2 = (const float*)d_in[5];
  const float* lw = (const float*)d_in[6];
  const float* lb = (const float*)d_in[7];
  float* out = (float*)d_out;
  int M = out_size / 4803;
  int Mpad = (M + 63) & ~63;

  auto align512 = [](size_t x) { return (x + 511) & ~(size_t)511; };
  size_t fixed = 0;
  fixed += align512((size_t)M*8*4);            // pairTab
  fixed += align512((size_t)86528*4);          // T
  fixed += align512((size_t)53248*2);          // W2B
  fixed += align512((size_t)4800*KPAD*2);      // Wt
  fixed += align512((size_t)Mpad*KPAD*2);      // X
  int splits = 4;
  while (splits > 1 && fixed + align512((size_t)splits*Mpad*NPAD*4) > ws_size) splits >>= 1;

  char* ws = (char*)d_ws;
  size_t off = 0;
  auto alloc = [&](size_t bytes) {
    off = align512(off);
    char* p = ws + off;
    off += bytes;
    return p;
  };
  int* pairTab = (int*)alloc((size_t)M*8*4);
  float* T = (float*)alloc((size_t)86528*4);
  unsigned short* W2B = (unsigned short*)alloc((size_t)53248*2);
  unsigned short* Wt = (unsigned short*)alloc((size_t)4800*KPAD*2);
  unsigned short* X = (unsigned short*)alloc((size_t)Mpad*KPAD*2);
  float* P = (splits > 1) ? (float*)alloc((size_t)splits*Mpad*NPAD*4) : nullptr;

  prep_pairs<<<1, 256, 0, stream>>>(bboxes, num_obj, M, pairTab, out + (size_t)M*4800);
  prep_tables<<<(86528+53248+255)/256, 256, 0, stream>>>(w1, b1, w2, T, W2B);
  prep_wt<<<dim3(85, 75), 256, 0, stream>>>(lw, Wt);
  pair_conv<<<M*3, 256, 0, stream>>>(pairTab, T, W2B, b2, X);
  gemm_lin<<<dim3(Mpad/64, 38, splits), 256, 0, stream>>>(X, Wt, lb, P, out, M, Mpad, splits);
  if (splits > 1)
    reduce_out<<<1024, 256, 0, stream>>>(P, lb, out, M, Mpad, splits);
}